// Round 3
// baseline (203982.361 us; speedup 1.0000x reference)
//
#include <hip/hip_runtime.h>
#include <hip/hip_bf16.h>

// B=64, S=512, I=256, H=512 LSTM forward.
// R8: XCD-pinned groups + L2-scope communication (R7 theory), hardened.
// R6 counters showed ~94% of step time is poll-latency wait: agent-scope
// publish/poll must round-trip the coherence point beyond the per-XCD L2
// (FETCH showed ~315MB of poll L2-misses; WRITE showed publishes written
// through). Fix: place each batch-group's 16 WGs on ONE XCD, communicate
// via sc0 (L1-bypass, L2-coherent) ops: ~200cy RT instead of ~900.
// Hardening vs R7 (which failed, no counters):
//  (1) workspace layout byte-identical to passing R6 — claim counters live
//      in the last 64B of `out` (c_f tail), which is legitimately rewritten
//      only at t=SS-1, long after all claims complete (arrival barrier).
//  (2) placement is VERIFIED, not assumed: all 256 WGs (1/CU forced by LDS)
//      claim per-XCD slots, pass a global arrival barrier (all co-resident
//      so it terminates), then check the final counts. All XCDs 0-3 with
//      >=16 WGs -> FAST mode (sc0 comm, XCD-pure groups). Otherwise ->
//      SAFE mode: re-claim globally, use R6's proven agent-scope comm.
//  (3) FAST-mode spin escalates to agent-scope loads after 1024 rounds
//      (same L2 resolves both scopes in an XCD-pure group) — a semantics
//      surprise degrades to slow-but-correct instead of hanging.
// Body otherwise identical to R6: U-slice + W-slice hoisted to VGPRs,
// h published as self-certifying u64 atoms (tag<<32 | 2xbf16), bulk
// 16-load poll with one combined tag check; the spin IS the group barrier.

#define BB 64
#define SS 512
#define II 256
#define HH 512
#define G4 2048
#define NGRP 4     // batch groups
#define GB 16      // batches per group
#define NWPG 16    // WGs per group
#define NCOL 128   // gate cols per WG = 4 gates x 32 units
#define NU 32      // hidden units per WG

typedef __attribute__((ext_vector_type(8))) short bf16x8;
typedef __attribute__((ext_vector_type(4))) float f32x4;
typedef unsigned long long u64t;

__device__ __forceinline__ u64t ld_llc_u64(const u64t* p) {
  return __hip_atomic_load((u64t*)p, __ATOMIC_RELAXED,
                           __HIP_MEMORY_SCOPE_AGENT);
}
__device__ __forceinline__ void st_llc_u64(u64t* p, u64t v) {
  __hip_atomic_store(p, v, __ATOMIC_RELAXED, __HIP_MEMORY_SCOPE_AGENT);
}

// x [b][t][i] fp32 -> xb [t][b][i] bf16
__global__ void convert_x_kernel(const float* __restrict__ x,
                                 __hip_bfloat16* __restrict__ xb) {
  int blk = blockIdx.x;          // b*SS + t
  int b = blk >> 9;
  int t = blk & (SS - 1);
  int i = threadIdx.x;
  xb[((size_t)t * BB + b) * II + i] = __float2bfloat16(x[(size_t)blk * II + i]);
}

// W [256][2048] fp32 -> Wt [2048][256] bf16 (row = gate col, for B-frags)
__global__ void transpose_w_kernel(const float* __restrict__ W,
                                   __hip_bfloat16* __restrict__ Wt) {
  __shared__ __hip_bfloat16 tile[64][64 + 8];
  int kb = blockIdx.x & 3;       // 4 k-blocks
  int nb = blockIdx.x >> 2;      // 32 n-blocks
  int k0 = kb * 64, nb0 = nb * 64;
#pragma unroll
  for (int p = 0; p < 16; ++p) {
    int r = p * 4 + (threadIdx.x >> 6);
    int c = threadIdx.x & 63;
    tile[r][c] = __float2bfloat16(W[(size_t)(k0 + r) * G4 + nb0 + c]);
  }
  __syncthreads();
#pragma unroll
  for (int p = 0; p < 16; ++p) {
    int n = p * 4 + (threadIdx.x >> 6);
    int k = threadIdx.x & 63;
    Wt[(size_t)(nb0 + n) * II + k0 + k] = tile[k][n];
  }
}

// wait for the 16 asm-issued sc0 loads, then fence the scheduler so no
// consumer of q[] is hoisted above the waitcnt (guide rule #18).
#define WAIT_Q()                                                        \
  asm volatile("s_waitcnt vmcnt(0)"                                     \
               : "+v"(q[0]), "+v"(q[1]), "+v"(q[2]), "+v"(q[3]),        \
                 "+v"(q[4]), "+v"(q[5]), "+v"(q[6]), "+v"(q[7]),        \
                 "+v"(q[8]), "+v"(q[9]), "+v"(q[10]), "+v"(q[11]),      \
                 "+v"(q[12]), "+v"(q[13]), "+v"(q[14]), "+v"(q[15])     \
               :: "memory");                                            \
  __builtin_amdgcn_sched_barrier(0)

__global__ __launch_bounds__(256, 1)
void lstm_step(const float* __restrict__ U,
               const float* __restrict__ bias,
               const __hip_bfloat16* __restrict__ xb,
               const __hip_bfloat16* __restrict__ Wt,
               u64t* __restrict__ hpub,   // [NGRP][2][GB*256] u64
               unsigned* cnt,  // 16 u32 in out-tail (aliases out: NO restrict)
               float* out) {
  // LDS: Ut 133.1K (staging only) + hL 16.6K + gate 8.4K + bias 0.5K = 158.7K
  __shared__ alignas(16) __hip_bfloat16 Ut[NCOL][HH + 8];
  __shared__ alignas(16) __hip_bfloat16 hL[GB][HH + 8];
  __shared__ float gate[GB][NCOL + 4];
  __shared__ float bia[NCOL];
  __shared__ int sh_grp, sh_w16, sh_fast;

  const int tid = threadIdx.x;

  // ---- claim + verified placement (cnt[0..7]=per-XCD claims, [9]=safe
  // pool, [15]=arrival count). All 256 WGs are co-resident (LDS forces
  // 1 WG/CU), so the arrival barrier always terminates, and ALL claims
  // complete before ANY WG starts the step loop.
  if (tid == 0) {
    unsigned xcc;
    asm volatile("s_getreg_b32 %0, hwreg(HW_REG_XCC_ID)" : "=s"(xcc));
    xcc &= 7u;
    unsigned my = __hip_atomic_fetch_add(&cnt[xcc], 1u, __ATOMIC_RELAXED,
                                         __HIP_MEMORY_SCOPE_AGENT);
    __hip_atomic_fetch_add(&cnt[15], 1u, __ATOMIC_RELEASE,
                           __HIP_MEMORY_SCOPE_AGENT);
    while (__hip_atomic_load(&cnt[15], __ATOMIC_ACQUIRE,
                             __HIP_MEMORY_SCOPE_AGENT) < 256u) {}
    unsigned c0 = __hip_atomic_load(&cnt[0], __ATOMIC_RELAXED,
                                    __HIP_MEMORY_SCOPE_AGENT);
    unsigned c1 = __hip_atomic_load(&cnt[1], __ATOMIC_RELAXED,
                                    __HIP_MEMORY_SCOPE_AGENT);
    unsigned c2 = __hip_atomic_load(&cnt[2], __ATOMIC_RELAXED,
                                    __HIP_MEMORY_SCOPE_AGENT);
    unsigned c3 = __hip_atomic_load(&cnt[3], __ATOMIC_RELAXED,
                                    __HIP_MEMORY_SCOPE_AGENT);
    int fast = (c0 >= NWPG && c1 >= NWPG && c2 >= NWPG && c3 >= NWPG);
    int grp = -1, w16 = 0;
    if (fast) {
      if (xcc < NGRP && my < NWPG) { grp = (int)xcc; w16 = (int)my; }
    } else {
      unsigned sp = __hip_atomic_fetch_add(&cnt[9], 1u, __ATOMIC_RELAXED,
                                           __HIP_MEMORY_SCOPE_AGENT);
      if (sp < NGRP * NWPG) { grp = (int)(sp >> 4); w16 = (int)(sp & 15); }
    }
    sh_grp = grp; sh_w16 = w16; sh_fast = fast;
  }
  __syncthreads();
  const int grp = sh_grp;
  const int w16 = sh_w16;
  const bool fast = (bool)sh_fast;
  if (grp < 0) return;             // uniform exit, CU freed
  const int n0 = w16 * NU;         // hidden-unit offset of this WG's slice

  // ---- one-time: stage U column-slice (transposed, bf16) + bias ----
  // local col c = g*32 + j  <->  global col g*512 + n0 + j
  for (int i = tid; i < NCOL * HH; i += 256) {
    int c = i & (NCOL - 1);
    int k = i >> 7;
    int g = c >> 5, j = c & 31;
    Ut[c][k] = __float2bfloat16(U[(size_t)k * G4 + g * HH + n0 + j]);
  }
  if (tid < NCOL) {
    int g = tid >> 5, j = tid & 31;
    bia[tid] = bias[g * HH + n0 + j];
  }
  __syncthreads();

  const int lane = tid & 63;
  const int wave = tid >> 6;
  const int l16 = lane & 15;
  const int quad = lane >> 4;
  const int c0i = (2 * wave) * 16 + l16;       // this lane's col, n-tile 0
  const int c1i = (2 * wave + 1) * 16 + l16;   // this lane's col, n-tile 1

  // ---- one-time: hoist step-invariant B-operands into VGPRs ----
  bf16x8 uf0[16], uf1[16];
#pragma unroll
  for (int ks = 0; ks < 16; ++ks) {
    uf0[ks] = *(const bf16x8*)(&Ut[c0i][ks * 32 + quad * 8]);
    uf1[ks] = *(const bf16x8*)(&Ut[c1i][ks * 32 + quad * 8]);
  }
  const __hip_bfloat16* wrow0 =
      Wt + (size_t)((c0i >> 5) * HH + n0 + (c0i & 31)) * II;
  const __hip_bfloat16* wrow1 =
      Wt + (size_t)((c1i >> 5) * HH + n0 + (c1i & 31)) * II;
  bf16x8 wf0[8], wf1[8];
#pragma unroll
  for (int ks = 0; ks < 8; ++ks) {
    wf0[ks] = *(const bf16x8*)(wrow0 + ks * 32 + quad * 8);
    wf1[ks] = *(const bf16x8*)(wrow1 + ks * 32 + quad * 8);
  }
  const float b0 = bia[c0i];
  const float b1 = bia[c1i];

  // eltwise ownership: thread -> cells (eb, ej) and (eb, ej+1)
  const int eb = (2 * tid) >> 5;   // batch-local 0..15
  const int ej = (2 * tid) & 31;   // even unit index 0..30
  float cs0 = 0.f, cs1 = 0.f;

  u64t* gbase = hpub + (size_t)grp * 2 * (GB * 256);

  for (int t = 0; t < SS; ++t) {
    const u64t* hr = gbase + (size_t)((t & 1) ^ 1) * (GB * 256) + tid;
    u64t* hw = gbase + (size_t)(t & 1) * (GB * 256);
    const unsigned ewant = (unsigned)t;
    const unsigned epub = (unsigned)(t + 1);

    // ---- bulk-issue this thread's 16 h-atoms (coalesced: batch k, col tid)
    u64t q[16];
    if (fast) {
      // sc0: bypass L1, resolve at the XCD's L2 (group is XCD-pure)
#pragma unroll
      for (int k = 0; k < 16; ++k)
        asm volatile("global_load_dwordx2 %0, %1, off sc0"
                     : "=v"(q[k]) : "v"(hr + k * 256) : "memory");
    } else {
#pragma unroll
      for (int k = 0; k < 16; ++k) q[k] = ld_llc_u64(hr + k * 256);
    }

    // ---- x @ W while atoms fly (independent of q) ----
    f32x4 acc0 = {b0, b0, b0, b0};
    f32x4 acc1 = {b1, b1, b1, b1};
    const __hip_bfloat16* xrow =
        xb + ((size_t)t * BB + grp * GB + l16) * II;
#pragma unroll
    for (int ks = 0; ks < II / 32; ++ks) {
      bf16x8 a = *(const bf16x8*)(xrow + ks * 32 + quad * 8);
      acc0 = __builtin_amdgcn_mfma_f32_16x16x32_bf16(a, wf0[ks], acc0, 0, 0, 0);
      acc1 = __builtin_amdgcn_mfma_f32_16x16x32_bf16(a, wf1[ks], acc1, 0, 0, 0);
    }

    // ---- ONE combined tag check; re-poll stale ----
    if (fast) { WAIT_Q(); }
    int rounds = 0;
    for (;;) {
      unsigned bad = 0;
#pragma unroll
      for (int k = 0; k < 16; ++k) bad |= ((unsigned)(q[k] >> 32) ^ ewant);
      if (bad == 0) break;
      if (fast && rounds < 1024) {
        ++rounds;
#pragma unroll
        for (int k = 0; k < 16; ++k)
          asm volatile("global_load_dwordx2 %0, %1, off sc0"
                       : "=v"(q[k]) : "v"(hr + k * 256) : "memory");
        WAIT_Q();
      } else {
        // SAFE mode, or FAST escalation (same L2 resolves both scopes in an
        // XCD-pure group): predicated agent-scope re-poll.
#pragma unroll
        for (int k = 0; k < 16; ++k)
          if ((unsigned)(q[k] >> 32) != ewant)
            q[k] = ld_llc_u64(hr + k * 256);
      }
    }

    // ---- scatter h payloads to LDS: thread owns cols (2*tid,2*tid+1) ----
#pragma unroll
    for (int k = 0; k < 16; ++k)
      *(unsigned*)(&hL[k][2 * tid]) = (unsigned)q[k];
    __syncthreads();   // SYNC#1: hL complete

    // ---- h @ U: A-frag from LDS, B-frag from registers ----
#pragma unroll
    for (int ks = 0; ks < HH / 32; ++ks) {
      bf16x8 a = *(const bf16x8*)(&hL[l16][ks * 32 + quad * 8]);
      acc0 = __builtin_amdgcn_mfma_f32_16x16x32_bf16(a, uf0[ks], acc0, 0, 0, 0);
      acc1 = __builtin_amdgcn_mfma_f32_16x16x32_bf16(a, uf1[ks], acc1, 0, 0, 0);
    }

    // D layout (verified m89): row = quad*4 + r (batch-local), col = lane's c
#pragma unroll
    for (int r = 0; r < 4; ++r) {
      gate[quad * 4 + r][c0i] = acc0[r];
      gate[quad * 4 + r][c1i] = acc1[r];
    }
    __syncthreads();   // SYNC#2: gates complete

    // ---- elementwise: 2 cells per thread ----
    float hv[2];
#pragma unroll
    for (int s = 0; s < 2; ++s) {
      int j = ej + s;
      float& cst = s ? cs1 : cs0;
      float xi = gate[eb][j];          // i
      float xf = gate[eb][32 + j];     // f
      float xg = gate[eb][64 + j];     // g
      float xo = gate[eb][96 + j];     // o
      float it = 1.f / (1.f + __expf(-xi));
      float ft = 1.f / (1.f + __expf(-xf));
      float gx = fminf(fmaxf(xg, -15.f), 15.f);
      float eg = __expf(2.f * gx);
      float gt = (eg - 1.f) / (eg + 1.f);
      float ot = 1.f / (1.f + __expf(-xo));
      cst = ft * cst + it * gt;
      float cc = fminf(fmaxf(cst, -15.f), 15.f);
      float ec = __expf(2.f * cc);
      float th = (ec - 1.f) / (ec + 1.f);
      hv[s] = ot * th;
    }

    // publish FIRST (critical path): tag<<32 | 2xbf16, one 8B atom
    union { __hip_bfloat16 h2[2]; unsigned u; } hp;
    hp.h2[0] = __float2bfloat16(hv[0]);
    hp.h2[1] = __float2bfloat16(hv[1]);
    u64t pubv = ((u64t)epub << 32) | (u64t)hp.u;
    u64t* paddr = hw + eb * 256 + w16 * 16 + (ej >> 1);
    if (fast) {
      asm volatile("global_store_dwordx2 %0, %1, off sc0"
                   :: "v"(paddr), "v"(pubv) : "memory");
    } else {
      st_llc_u64(paddr, pubv);
    }

    // outputs
    int bglob = grp * GB + eb;
    int hglob = n0 + ej;
    *(float2*)(out + ((size_t)bglob * SS + t) * HH + hglob) =
        make_float2(hv[0], hv[1]);
    if (t == SS - 1) {
      size_t base = (size_t)BB * SS * HH;
      *(float2*)(out + base + (size_t)bglob * HH + hglob) =
          make_float2(hv[0], hv[1]);                        // h_f
      *(float2*)(out + base + (size_t)BB * HH + (size_t)bglob * HH + hglob) =
          make_float2(cs0, cs1);                            // c_f
    }
  }
}

extern "C" void kernel_launch(void* const* d_in, const int* in_sizes, int n_in,
                              void* d_out, int out_size, void* d_ws, size_t ws_size,
                              hipStream_t stream) {
  const float* x = (const float*)d_in[0];     // [64,512,256]
  const float* W = (const float*)d_in[1];     // [256,2048]
  const float* U = (const float*)d_in[2];     // [512,2048]
  const float* bias = (const float*)d_in[3];  // [2048]
  float* out = (float*)d_out;

  // ws layout byte-identical to R6 (no growth):
  char* ws = (char*)d_ws;
  u64t* hpub = (u64t*)ws;                                   // 256 KB
  __hip_bfloat16* Wt = (__hip_bfloat16*)(ws + 256 * 1024);  // 1 MB
  __hip_bfloat16* xb =
      (__hip_bfloat16*)(ws + 256 * 1024 + (size_t)G4 * II * 2);  // 16 MB

  // claim counters: last 64B of out (c_f tail). Claims all complete before
  // any WG steps (arrival barrier); the region is legitimately rewritten
  // with real c_f values at t=SS-1.
  unsigned* cnt = (unsigned*)((char*)d_out + out_size - 64);

  // zero hpub (tag 0 == epoch of h(-1), payload 0 == h(-1)=0) + counters
  hipMemsetAsync(d_ws, 0, 256 * 1024, stream);
  hipMemsetAsync(cnt, 0, 64, stream);
  convert_x_kernel<<<BB * SS, II, 0, stream>>>(x, xb);
  transpose_w_kernel<<<128, 256, 0, stream>>>(W, Wt);
  // 256 WGs: LDS forces 1 WG/CU -> full chip; 64 claim work, rest exit.
  lstm_step<<<256, 256, 0, stream>>>(U, bias, xb, Wt, hpub, cnt, out);
}

// Round 4
// 1766.390 us; speedup vs baseline: 115.4798x; 115.4798x over previous
//
#include <hip/hip_runtime.h>
#include <hip/hip_bf16.h>

// B=64, S=512, I=256, H=512 LSTM forward.
// R9: XCD-pure groups with L2-local communication, recombining the two
// halves that R8 MEASURED as working:
//   - publish: sc0 global store  -> stays DIRTY in the local XCD L2
//     (R8: WRITE_SIZE collapsed 131->66MB = out only)
//   - poll: agent-scope relaxed load -> observes sc0-stored data AND
//     resolves in the local L2 with no fabric traffic
//     (R8: escalated agent polls sustained the whole run, passed, with
//      FETCH_SIZE ~30MB = weights+x only)
// R8's only defect was polling with sc0 (SE-scope encoding; served stale
// from per-CU L1 -> every step burned a 1024-round dead-poll budget ->
// 204ms). R9 polls agent-scope from the start; no escalation needed.
// Placement machinery identical to R8 (proven): 256 WGs (LDS forces
// 1 WG/CU -> full chip), per-XCD claim via HW_REG_XCC_ID + global arrival
// barrier + verified counts; FAST (XCD-pure groups, sc0 publish) vs SAFE
// (R6's agent publish) is a uniform runtime flag. Poll path is now
// mode-independent; only the publish instruction differs.
// Body identical to R6: U-slice + W-slice hoisted to VGPRs, h published as
// self-certifying u64 atoms (tag<<32 | 2xbf16), bulk 16-load poll with one
// combined tag check + predicated re-poll; the spin IS the group barrier.

#define BB 64
#define SS 512
#define II 256
#define HH 512
#define G4 2048
#define NGRP 4     // batch groups
#define GB 16      // batches per group
#define NWPG 16    // WGs per group
#define NCOL 128   // gate cols per WG = 4 gates x 32 units
#define NU 32      // hidden units per WG

typedef __attribute__((ext_vector_type(8))) short bf16x8;
typedef __attribute__((ext_vector_type(4))) float f32x4;
typedef unsigned long long u64t;

__device__ __forceinline__ u64t ld_llc_u64(const u64t* p) {
  return __hip_atomic_load((u64t*)p, __ATOMIC_RELAXED,
                           __HIP_MEMORY_SCOPE_AGENT);
}
__device__ __forceinline__ void st_llc_u64(u64t* p, u64t v) {
  __hip_atomic_store(p, v, __ATOMIC_RELAXED, __HIP_MEMORY_SCOPE_AGENT);
}

// x [b][t][i] fp32 -> xb [t][b][i] bf16
__global__ void convert_x_kernel(const float* __restrict__ x,
                                 __hip_bfloat16* __restrict__ xb) {
  int blk = blockIdx.x;          // b*SS + t
  int b = blk >> 9;
  int t = blk & (SS - 1);
  int i = threadIdx.x;
  xb[((size_t)t * BB + b) * II + i] = __float2bfloat16(x[(size_t)blk * II + i]);
}

// W [256][2048] fp32 -> Wt [2048][256] bf16 (row = gate col, for B-frags)
__global__ void transpose_w_kernel(const float* __restrict__ W,
                                   __hip_bfloat16* __restrict__ Wt) {
  __shared__ __hip_bfloat16 tile[64][64 + 8];
  int kb = blockIdx.x & 3;       // 4 k-blocks
  int nb = blockIdx.x >> 2;      // 32 n-blocks
  int k0 = kb * 64, nb0 = nb * 64;
#pragma unroll
  for (int p = 0; p < 16; ++p) {
    int r = p * 4 + (threadIdx.x >> 6);
    int c = threadIdx.x & 63;
    tile[r][c] = __float2bfloat16(W[(size_t)(k0 + r) * G4 + nb0 + c]);
  }
  __syncthreads();
#pragma unroll
  for (int p = 0; p < 16; ++p) {
    int n = p * 4 + (threadIdx.x >> 6);
    int k = threadIdx.x & 63;
    Wt[(size_t)(nb0 + n) * II + k0 + k] = tile[k][n];
  }
}

__global__ __launch_bounds__(256, 1)
void lstm_step(const float* __restrict__ U,
               const float* __restrict__ bias,
               const __hip_bfloat16* __restrict__ xb,
               const __hip_bfloat16* __restrict__ Wt,
               u64t* __restrict__ hpub,   // [NGRP][2][GB*256] u64
               unsigned* cnt,  // 16 u32 in out-tail (aliases out: NO restrict)
               float* out) {
  // LDS: Ut 133.1K (staging only) + hL 16.6K + gate 8.4K + bias 0.5K = 158.7K
  __shared__ alignas(16) __hip_bfloat16 Ut[NCOL][HH + 8];
  __shared__ alignas(16) __hip_bfloat16 hL[GB][HH + 8];
  __shared__ float gate[GB][NCOL + 4];
  __shared__ float bia[NCOL];
  __shared__ int sh_grp, sh_w16, sh_fast;

  const int tid = threadIdx.x;

  // ---- claim + verified placement (cnt[0..7]=per-XCD claims, [9]=safe
  // pool, [15]=arrival count). All 256 WGs are co-resident (LDS forces
  // 1 WG/CU), so the arrival barrier always terminates, and ALL claims
  // complete before ANY WG starts the step loop.
  if (tid == 0) {
    unsigned xcc;
    asm volatile("s_getreg_b32 %0, hwreg(HW_REG_XCC_ID)" : "=s"(xcc));
    xcc &= 7u;
    unsigned my = __hip_atomic_fetch_add(&cnt[xcc], 1u, __ATOMIC_RELAXED,
                                         __HIP_MEMORY_SCOPE_AGENT);
    __hip_atomic_fetch_add(&cnt[15], 1u, __ATOMIC_RELEASE,
                           __HIP_MEMORY_SCOPE_AGENT);
    while (__hip_atomic_load(&cnt[15], __ATOMIC_ACQUIRE,
                             __HIP_MEMORY_SCOPE_AGENT) < 256u) {}
    unsigned c0 = __hip_atomic_load(&cnt[0], __ATOMIC_RELAXED,
                                    __HIP_MEMORY_SCOPE_AGENT);
    unsigned c1 = __hip_atomic_load(&cnt[1], __ATOMIC_RELAXED,
                                    __HIP_MEMORY_SCOPE_AGENT);
    unsigned c2 = __hip_atomic_load(&cnt[2], __ATOMIC_RELAXED,
                                    __HIP_MEMORY_SCOPE_AGENT);
    unsigned c3 = __hip_atomic_load(&cnt[3], __ATOMIC_RELAXED,
                                    __HIP_MEMORY_SCOPE_AGENT);
    int fast = (c0 >= NWPG && c1 >= NWPG && c2 >= NWPG && c3 >= NWPG);
    int grp = -1, w16 = 0;
    if (fast) {
      if (xcc < NGRP && my < NWPG) { grp = (int)xcc; w16 = (int)my; }
    } else {
      unsigned sp = __hip_atomic_fetch_add(&cnt[9], 1u, __ATOMIC_RELAXED,
                                           __HIP_MEMORY_SCOPE_AGENT);
      if (sp < NGRP * NWPG) { grp = (int)(sp >> 4); w16 = (int)(sp & 15); }
    }
    sh_grp = grp; sh_w16 = w16; sh_fast = fast;
  }
  __syncthreads();
  const int grp = sh_grp;
  const int w16 = sh_w16;
  const bool fast = (bool)sh_fast;
  if (grp < 0) return;             // uniform exit, CU freed
  const int n0 = w16 * NU;         // hidden-unit offset of this WG's slice

  // ---- one-time: stage U column-slice (transposed, bf16) + bias ----
  // local col c = g*32 + j  <->  global col g*512 + n0 + j
  for (int i = tid; i < NCOL * HH; i += 256) {
    int c = i & (NCOL - 1);
    int k = i >> 7;
    int g = c >> 5, j = c & 31;
    Ut[c][k] = __float2bfloat16(U[(size_t)k * G4 + g * HH + n0 + j]);
  }
  if (tid < NCOL) {
    int g = tid >> 5, j = tid & 31;
    bia[tid] = bias[g * HH + n0 + j];
  }
  __syncthreads();

  const int lane = tid & 63;
  const int wave = tid >> 6;
  const int l16 = lane & 15;
  const int quad = lane >> 4;
  const int c0i = (2 * wave) * 16 + l16;       // this lane's col, n-tile 0
  const int c1i = (2 * wave + 1) * 16 + l16;   // this lane's col, n-tile 1

  // ---- one-time: hoist step-invariant B-operands into VGPRs ----
  bf16x8 uf0[16], uf1[16];
#pragma unroll
  for (int ks = 0; ks < 16; ++ks) {
    uf0[ks] = *(const bf16x8*)(&Ut[c0i][ks * 32 + quad * 8]);
    uf1[ks] = *(const bf16x8*)(&Ut[c1i][ks * 32 + quad * 8]);
  }
  const __hip_bfloat16* wrow0 =
      Wt + (size_t)((c0i >> 5) * HH + n0 + (c0i & 31)) * II;
  const __hip_bfloat16* wrow1 =
      Wt + (size_t)((c1i >> 5) * HH + n0 + (c1i & 31)) * II;
  bf16x8 wf0[8], wf1[8];
#pragma unroll
  for (int ks = 0; ks < 8; ++ks) {
    wf0[ks] = *(const bf16x8*)(wrow0 + ks * 32 + quad * 8);
    wf1[ks] = *(const bf16x8*)(wrow1 + ks * 32 + quad * 8);
  }
  const float b0 = bia[c0i];
  const float b1 = bia[c1i];

  // eltwise ownership: thread -> cells (eb, ej) and (eb, ej+1)
  const int eb = (2 * tid) >> 5;   // batch-local 0..15
  const int ej = (2 * tid) & 31;   // even unit index 0..30
  float cs0 = 0.f, cs1 = 0.f;

  u64t* gbase = hpub + (size_t)grp * 2 * (GB * 256);

  for (int t = 0; t < SS; ++t) {
    const u64t* hr = gbase + (size_t)((t & 1) ^ 1) * (GB * 256) + tid;
    u64t* hw = gbase + (size_t)(t & 1) * (GB * 256);
    const unsigned ewant = (unsigned)t;
    const unsigned epub = (unsigned)(t + 1);

    // ---- bulk-issue this thread's 16 h-atoms (coalesced: batch k, col tid).
    // Agent-scope loads: bypass stale L1; in FAST mode the line is dirty in
    // this XCD's L2 and resolves there (R8-measured: no fabric fetches).
    u64t q[16];
#pragma unroll
    for (int k = 0; k < 16; ++k) q[k] = ld_llc_u64(hr + k * 256);

    // ---- x @ W while atoms fly (independent of q) ----
    f32x4 acc0 = {b0, b0, b0, b0};
    f32x4 acc1 = {b1, b1, b1, b1};
    const __hip_bfloat16* xrow =
        xb + ((size_t)t * BB + grp * GB + l16) * II;
#pragma unroll
    for (int ks = 0; ks < II / 32; ++ks) {
      bf16x8 a = *(const bf16x8*)(xrow + ks * 32 + quad * 8);
      acc0 = __builtin_amdgcn_mfma_f32_16x16x32_bf16(a, wf0[ks], acc0, 0, 0, 0);
      acc1 = __builtin_amdgcn_mfma_f32_16x16x32_bf16(a, wf1[ks], acc1, 0, 0, 0);
    }

    // ---- ONE combined tag check; predicated re-poll of stale atoms only
    for (;;) {
      unsigned bad = 0;
#pragma unroll
      for (int k = 0; k < 16; ++k) bad |= ((unsigned)(q[k] >> 32) ^ ewant);
      if (bad == 0) break;
#pragma unroll
      for (int k = 0; k < 16; ++k)
        if ((unsigned)(q[k] >> 32) != ewant)
          q[k] = ld_llc_u64(hr + k * 256);
    }

    // ---- scatter h payloads to LDS: thread owns cols (2*tid,2*tid+1) ----
#pragma unroll
    for (int k = 0; k < 16; ++k)
      *(unsigned*)(&hL[k][2 * tid]) = (unsigned)q[k];
    __syncthreads();   // SYNC#1: hL complete

    // ---- h @ U: A-frag from LDS, B-frag from registers ----
#pragma unroll
    for (int ks = 0; ks < HH / 32; ++ks) {
      bf16x8 a = *(const bf16x8*)(&hL[l16][ks * 32 + quad * 8]);
      acc0 = __builtin_amdgcn_mfma_f32_16x16x32_bf16(a, uf0[ks], acc0, 0, 0, 0);
      acc1 = __builtin_amdgcn_mfma_f32_16x16x32_bf16(a, uf1[ks], acc1, 0, 0, 0);
    }

    // D layout (verified m89): row = quad*4 + r (batch-local), col = lane's c
#pragma unroll
    for (int r = 0; r < 4; ++r) {
      gate[quad * 4 + r][c0i] = acc0[r];
      gate[quad * 4 + r][c1i] = acc1[r];
    }
    __syncthreads();   // SYNC#2: gates complete

    // ---- elementwise: 2 cells per thread ----
    float hv[2];
#pragma unroll
    for (int s = 0; s < 2; ++s) {
      int j = ej + s;
      float& cst = s ? cs1 : cs0;
      float xi = gate[eb][j];          // i
      float xf = gate[eb][32 + j];     // f
      float xg = gate[eb][64 + j];     // g
      float xo = gate[eb][96 + j];     // o
      float it = 1.f / (1.f + __expf(-xi));
      float ft = 1.f / (1.f + __expf(-xf));
      float gx = fminf(fmaxf(xg, -15.f), 15.f);
      float eg = __expf(2.f * gx);
      float gt = (eg - 1.f) / (eg + 1.f);
      float ot = 1.f / (1.f + __expf(-xo));
      cst = ft * cst + it * gt;
      float cc = fminf(fmaxf(cst, -15.f), 15.f);
      float ec = __expf(2.f * cc);
      float th = (ec - 1.f) / (ec + 1.f);
      hv[s] = ot * th;
    }

    // publish FIRST (critical path): tag<<32 | 2xbf16, one 8B atom.
    // FAST: sc0 store -> dirty in local L2, visible to agent loads
    // (both properties R8-measured). SAFE: R6's agent store.
    union { __hip_bfloat16 h2[2]; unsigned u; } hp;
    hp.h2[0] = __float2bfloat16(hv[0]);
    hp.h2[1] = __float2bfloat16(hv[1]);
    u64t pubv = ((u64t)epub << 32) | (u64t)hp.u;
    u64t* paddr = hw + eb * 256 + w16 * 16 + (ej >> 1);
    if (fast) {
      asm volatile("global_store_dwordx2 %0, %1, off sc0"
                   :: "v"(paddr), "v"(pubv) : "memory");
    } else {
      st_llc_u64(paddr, pubv);
    }

    // outputs
    int bglob = grp * GB + eb;
    int hglob = n0 + ej;
    *(float2*)(out + ((size_t)bglob * SS + t) * HH + hglob) =
        make_float2(hv[0], hv[1]);
    if (t == SS - 1) {
      size_t base = (size_t)BB * SS * HH;
      *(float2*)(out + base + (size_t)bglob * HH + hglob) =
          make_float2(hv[0], hv[1]);                        // h_f
      *(float2*)(out + base + (size_t)BB * HH + (size_t)bglob * HH + hglob) =
          make_float2(cs0, cs1);                            // c_f
    }
  }
}

extern "C" void kernel_launch(void* const* d_in, const int* in_sizes, int n_in,
                              void* d_out, int out_size, void* d_ws, size_t ws_size,
                              hipStream_t stream) {
  const float* x = (const float*)d_in[0];     // [64,512,256]
  const float* W = (const float*)d_in[1];     // [256,2048]
  const float* U = (const float*)d_in[2];     // [512,2048]
  const float* bias = (const float*)d_in[3];  // [2048]
  float* out = (float*)d_out;

  // ws layout byte-identical to R6 (no growth):
  char* ws = (char*)d_ws;
  u64t* hpub = (u64t*)ws;                                   // 256 KB
  __hip_bfloat16* Wt = (__hip_bfloat16*)(ws + 256 * 1024);  // 1 MB
  __hip_bfloat16* xb =
      (__hip_bfloat16*)(ws + 256 * 1024 + (size_t)G4 * II * 2);  // 16 MB

  // claim counters: last 64B of out (c_f tail). Claims all complete before
  // any WG steps (arrival barrier); the region is legitimately rewritten
  // with real c_f values at t=SS-1.
  unsigned* cnt = (unsigned*)((char*)d_out + out_size - 64);

  // zero hpub (tag 0 == epoch of h(-1), payload 0 == h(-1)=0) + counters
  hipMemsetAsync(d_ws, 0, 256 * 1024, stream);
  hipMemsetAsync(cnt, 0, 64, stream);
  convert_x_kernel<<<BB * SS, II, 0, stream>>>(x, xb);
  transpose_w_kernel<<<128, 256, 0, stream>>>(W, Wt);
  // 256 WGs: LDS forces 1 WG/CU -> full chip; 64 claim work, rest exit.
  lstm_step<<<256, 256, 0, stream>>>(U, bias, xb, Wt, hpub, cnt, out);
}

// Round 5
// 1486.179 us; speedup vs baseline: 137.2529x; 1.1885x over previous
//
#include <hip/hip_runtime.h>
#include <hip/hip_bf16.h>

// B=64, S=512, I=256, H=512 LSTM forward.
// R10: chain-scheduling polish on R9's XCD-local communication.
// R6->R9 two-point fit (RT 900 vs 250cy) gives N~2 serialized round-trips
// and C~7500cy of per-step constant: comm latency is NOT the bottleneck
// anymore; the serial chain is. Two chain cuts:
//  (1) xb(t+1) prefetched into VGPRs during step t's h@U phase (~2000cy of
//      cover): x@W becomes pure register MFMA, removing a ~900cy cold-HBM
//      load stall from inside the serial loop (xb is streamed once; R9
//      FETCH=18.6MB confirms no L2 residency).
//  (2) tail reorder: publish -> issue polls(t+1) -> out stores, pinned with
//      sched_barrier(0). Poll loads precede out-stores in the vmcnt queue,
//      so the compiler's wait before the tag check no longer serializes on
//      store acks, and the poll RT overlaps the (short) x@W.
// Everything else identical to R9 (passed, FAST engaged): per-XCD claim via
// HW_REG_XCC_ID + arrival barrier + verified counts; publish = sc0 store
// (stays dirty in local L2, R8-measured); poll = agent-scope relaxed load
// (observes sc0 data, L2-local, R8-measured); h as self-certifying u64
// atoms (tag<<32 | 2xbf16); U/W slices resident in VGPRs.

#define BB 64
#define SS 512
#define II 256
#define HH 512
#define G4 2048
#define NGRP 4     // batch groups
#define GB 16      // batches per group
#define NWPG 16    // WGs per group
#define NCOL 128   // gate cols per WG = 4 gates x 32 units
#define NU 32      // hidden units per WG

typedef __attribute__((ext_vector_type(8))) short bf16x8;
typedef __attribute__((ext_vector_type(4))) float f32x4;
typedef unsigned long long u64t;

__device__ __forceinline__ u64t ld_llc_u64(const u64t* p) {
  return __hip_atomic_load((u64t*)p, __ATOMIC_RELAXED,
                           __HIP_MEMORY_SCOPE_AGENT);
}
__device__ __forceinline__ void st_llc_u64(u64t* p, u64t v) {
  __hip_atomic_store(p, v, __ATOMIC_RELAXED, __HIP_MEMORY_SCOPE_AGENT);
}

// x [b][t][i] fp32 -> xb [t][b][i] bf16
__global__ void convert_x_kernel(const float* __restrict__ x,
                                 __hip_bfloat16* __restrict__ xb) {
  int blk = blockIdx.x;          // b*SS + t
  int b = blk >> 9;
  int t = blk & (SS - 1);
  int i = threadIdx.x;
  xb[((size_t)t * BB + b) * II + i] = __float2bfloat16(x[(size_t)blk * II + i]);
}

// W [256][2048] fp32 -> Wt [2048][256] bf16 (row = gate col, for B-frags)
__global__ void transpose_w_kernel(const float* __restrict__ W,
                                   __hip_bfloat16* __restrict__ Wt) {
  __shared__ __hip_bfloat16 tile[64][64 + 8];
  int kb = blockIdx.x & 3;       // 4 k-blocks
  int nb = blockIdx.x >> 2;      // 32 n-blocks
  int k0 = kb * 64, nb0 = nb * 64;
#pragma unroll
  for (int p = 0; p < 16; ++p) {
    int r = p * 4 + (threadIdx.x >> 6);
    int c = threadIdx.x & 63;
    tile[r][c] = __float2bfloat16(W[(size_t)(k0 + r) * G4 + nb0 + c]);
  }
  __syncthreads();
#pragma unroll
  for (int p = 0; p < 16; ++p) {
    int n = p * 4 + (threadIdx.x >> 6);
    int k = threadIdx.x & 63;
    Wt[(size_t)(nb0 + n) * II + k0 + k] = tile[k][n];
  }
}

__global__ __launch_bounds__(256, 1)
void lstm_step(const float* __restrict__ U,
               const float* __restrict__ bias,
               const __hip_bfloat16* __restrict__ xb,
               const __hip_bfloat16* __restrict__ Wt,
               u64t* __restrict__ hpub,   // [NGRP][2][GB*256] u64
               unsigned* cnt,  // 16 u32 in out-tail (aliases out: NO restrict)
               float* out) {
  // LDS: Ut 133.1K (staging only) + hL 16.6K + gate 8.4K + bias 0.5K = 158.7K
  __shared__ alignas(16) __hip_bfloat16 Ut[NCOL][HH + 8];
  __shared__ alignas(16) __hip_bfloat16 hL[GB][HH + 8];
  __shared__ float gate[GB][NCOL + 4];
  __shared__ float bia[NCOL];
  __shared__ int sh_grp, sh_w16, sh_fast;

  const int tid = threadIdx.x;

  // ---- claim + verified placement (cnt[0..7]=per-XCD claims, [9]=safe
  // pool, [15]=arrival count). All 256 WGs are co-resident (LDS forces
  // 1 WG/CU), so the arrival barrier always terminates, and ALL claims
  // complete before ANY WG starts the step loop.
  if (tid == 0) {
    unsigned xcc;
    asm volatile("s_getreg_b32 %0, hwreg(HW_REG_XCC_ID)" : "=s"(xcc));
    xcc &= 7u;
    unsigned my = __hip_atomic_fetch_add(&cnt[xcc], 1u, __ATOMIC_RELAXED,
                                         __HIP_MEMORY_SCOPE_AGENT);
    __hip_atomic_fetch_add(&cnt[15], 1u, __ATOMIC_RELEASE,
                           __HIP_MEMORY_SCOPE_AGENT);
    while (__hip_atomic_load(&cnt[15], __ATOMIC_ACQUIRE,
                             __HIP_MEMORY_SCOPE_AGENT) < 256u) {}
    unsigned c0 = __hip_atomic_load(&cnt[0], __ATOMIC_RELAXED,
                                    __HIP_MEMORY_SCOPE_AGENT);
    unsigned c1 = __hip_atomic_load(&cnt[1], __ATOMIC_RELAXED,
                                    __HIP_MEMORY_SCOPE_AGENT);
    unsigned c2 = __hip_atomic_load(&cnt[2], __ATOMIC_RELAXED,
                                    __HIP_MEMORY_SCOPE_AGENT);
    unsigned c3 = __hip_atomic_load(&cnt[3], __ATOMIC_RELAXED,
                                    __HIP_MEMORY_SCOPE_AGENT);
    int fast = (c0 >= NWPG && c1 >= NWPG && c2 >= NWPG && c3 >= NWPG);
    int grp = -1, w16 = 0;
    if (fast) {
      if (xcc < NGRP && my < NWPG) { grp = (int)xcc; w16 = (int)my; }
    } else {
      unsigned sp = __hip_atomic_fetch_add(&cnt[9], 1u, __ATOMIC_RELAXED,
                                           __HIP_MEMORY_SCOPE_AGENT);
      if (sp < NGRP * NWPG) { grp = (int)(sp >> 4); w16 = (int)(sp & 15); }
    }
    sh_grp = grp; sh_w16 = w16; sh_fast = fast;
  }
  __syncthreads();
  const int grp = sh_grp;
  const int w16 = sh_w16;
  const bool fast = (bool)sh_fast;
  if (grp < 0) return;             // uniform exit, CU freed
  const int n0 = w16 * NU;         // hidden-unit offset of this WG's slice

  // ---- one-time: stage U column-slice (transposed, bf16) + bias ----
  // local col c = g*32 + j  <->  global col g*512 + n0 + j
  for (int i = tid; i < NCOL * HH; i += 256) {
    int c = i & (NCOL - 1);
    int k = i >> 7;
    int g = c >> 5, j = c & 31;
    Ut[c][k] = __float2bfloat16(U[(size_t)k * G4 + g * HH + n0 + j]);
  }
  if (tid < NCOL) {
    int g = tid >> 5, j = tid & 31;
    bia[tid] = bias[g * HH + n0 + j];
  }
  __syncthreads();

  const int lane = tid & 63;
  const int wave = tid >> 6;
  const int l16 = lane & 15;
  const int quad = lane >> 4;
  const int c0i = (2 * wave) * 16 + l16;       // this lane's col, n-tile 0
  const int c1i = (2 * wave + 1) * 16 + l16;   // this lane's col, n-tile 1

  // ---- one-time: hoist step-invariant B-operands into VGPRs ----
  bf16x8 uf0[16], uf1[16];
#pragma unroll
  for (int ks = 0; ks < 16; ++ks) {
    uf0[ks] = *(const bf16x8*)(&Ut[c0i][ks * 32 + quad * 8]);
    uf1[ks] = *(const bf16x8*)(&Ut[c1i][ks * 32 + quad * 8]);
  }
  const __hip_bfloat16* wrow0 =
      Wt + (size_t)((c0i >> 5) * HH + n0 + (c0i & 31)) * II;
  const __hip_bfloat16* wrow1 =
      Wt + (size_t)((c1i >> 5) * HH + n0 + (c1i & 31)) * II;
  bf16x8 wf0[8], wf1[8];
#pragma unroll
  for (int ks = 0; ks < 8; ++ks) {
    wf0[ks] = *(const bf16x8*)(wrow0 + ks * 32 + quad * 8);
    wf1[ks] = *(const bf16x8*)(wrow1 + ks * 32 + quad * 8);
  }
  const float b0 = bia[c0i];
  const float b1 = bia[c1i];

  // eltwise ownership: thread -> cells (eb, ej) and (eb, ej+1)
  const int eb = (2 * tid) >> 5;   // batch-local 0..15
  const int ej = (2 * tid) & 31;   // even unit index 0..30
  float cs0 = 0.f, cs1 = 0.f;

  u64t* gbase = hpub + (size_t)grp * 2 * (GB * 256);

  // ---- prologue: prefetch xb(0) into regs; issue polls(0) ----
  bf16x8 xr[8];
  {
    const __hip_bfloat16* xrow = xb + ((size_t)0 * BB + grp * GB + l16) * II;
#pragma unroll
    for (int ks = 0; ks < 8; ++ks)
      xr[ks] = *(const bf16x8*)(xrow + ks * 32 + quad * 8);
  }
  u64t q[16];
  {
    const u64t* hr0 = gbase + (size_t)1 * (GB * 256) + tid;  // (0&1)^1 = 1
#pragma unroll
    for (int k = 0; k < 16; ++k) q[k] = ld_llc_u64(hr0 + k * 256);
  }

  for (int t = 0; t < SS; ++t) {
    const u64t* hr = gbase + (size_t)((t & 1) ^ 1) * (GB * 256) + tid;
    u64t* hw = gbase + (size_t)(t & 1) * (GB * 256);
    const unsigned ewant = (unsigned)t;
    const unsigned epub = (unsigned)(t + 1);

    // ---- x @ W from prefetched registers (no VMEM on this path) ----
    f32x4 acc0 = {b0, b0, b0, b0};
    f32x4 acc1 = {b1, b1, b1, b1};
#pragma unroll
    for (int ks = 0; ks < II / 32; ++ks) {
      acc0 = __builtin_amdgcn_mfma_f32_16x16x32_bf16(xr[ks], wf0[ks], acc0, 0, 0, 0);
      acc1 = __builtin_amdgcn_mfma_f32_16x16x32_bf16(xr[ks], wf1[ks], acc1, 0, 0, 0);
    }

    // ---- ONE combined tag check; predicated re-poll of stale atoms only
    // (polls for this step were issued at the tail of the previous step)
    for (;;) {
      unsigned bad = 0;
#pragma unroll
      for (int k = 0; k < 16; ++k) bad |= ((unsigned)(q[k] >> 32) ^ ewant);
      if (bad == 0) break;
#pragma unroll
      for (int k = 0; k < 16; ++k)
        if ((unsigned)(q[k] >> 32) != ewant)
          q[k] = ld_llc_u64(hr + k * 256);
    }

    // ---- scatter h payloads to LDS: thread owns cols (2*tid,2*tid+1) ----
#pragma unroll
    for (int k = 0; k < 16; ++k)
      *(unsigned*)(&hL[k][2 * tid]) = (unsigned)q[k];

    // ---- prefetch xb(t+1) into regs; lands during h@U (~2000cy of cover)
    if (t + 1 < SS) {
      const __hip_bfloat16* xrow =
          xb + ((size_t)(t + 1) * BB + grp * GB + l16) * II;
#pragma unroll
      for (int ks = 0; ks < 8; ++ks)
        xr[ks] = *(const bf16x8*)(xrow + ks * 32 + quad * 8);
    }
    __syncthreads();   // SYNC#1: hL complete

    // ---- h @ U: A-frag from LDS, B-frag from registers ----
#pragma unroll
    for (int ks = 0; ks < HH / 32; ++ks) {
      bf16x8 a = *(const bf16x8*)(&hL[l16][ks * 32 + quad * 8]);
      acc0 = __builtin_amdgcn_mfma_f32_16x16x32_bf16(a, uf0[ks], acc0, 0, 0, 0);
      acc1 = __builtin_amdgcn_mfma_f32_16x16x32_bf16(a, uf1[ks], acc1, 0, 0, 0);
    }

    // D layout (verified m89): row = quad*4 + r (batch-local), col = lane's c
#pragma unroll
    for (int r = 0; r < 4; ++r) {
      gate[quad * 4 + r][c0i] = acc0[r];
      gate[quad * 4 + r][c1i] = acc1[r];
    }
    __syncthreads();   // SYNC#2: gates complete

    // ---- elementwise: 2 cells per thread ----
    float hv[2];
#pragma unroll
    for (int s = 0; s < 2; ++s) {
      int j = ej + s;
      float& cst = s ? cs1 : cs0;
      float xi = gate[eb][j];          // i
      float xf = gate[eb][32 + j];     // f
      float xg = gate[eb][64 + j];     // g
      float xo = gate[eb][96 + j];     // o
      float it = 1.f / (1.f + __expf(-xi));
      float ft = 1.f / (1.f + __expf(-xf));
      float gx = fminf(fmaxf(xg, -15.f), 15.f);
      float eg = __expf(2.f * gx);
      float gt = (eg - 1.f) / (eg + 1.f);
      float ot = 1.f / (1.f + __expf(-xo));
      cst = ft * cst + it * gt;
      float cc = fminf(fmaxf(cst, -15.f), 15.f);
      float ec = __expf(2.f * cc);
      float th = (ec - 1.f) / (ec + 1.f);
      hv[s] = ot * th;
    }

    // ---- publish FIRST (critical path): tag<<32 | 2xbf16, one 8B atom.
    union { __hip_bfloat16 h2[2]; unsigned u; } hp;
    hp.h2[0] = __float2bfloat16(hv[0]);
    hp.h2[1] = __float2bfloat16(hv[1]);
    u64t pubv = ((u64t)epub << 32) | (u64t)hp.u;
    u64t* paddr = hw + eb * 256 + w16 * 16 + (ej >> 1);
    if (fast) {
      asm volatile("global_store_dwordx2 %0, %1, off sc0"
                   :: "v"(paddr), "v"(pubv) : "memory");
    } else {
      st_llc_u64(paddr, pubv);
    }
    __builtin_amdgcn_sched_barrier(0);

    // ---- issue polls(t+1) BEFORE the out stores: they precede the stores
    // in the vmcnt queue, so next step's tag check never waits store acks,
    // and their RT overlaps next step's (register-only) x@W.
    if (t + 1 < SS) {
      const u64t* hrn = gbase + (size_t)(t & 1) * (GB * 256) + tid;
#pragma unroll
      for (int k = 0; k < 16; ++k) q[k] = ld_llc_u64(hrn + k * 256);
    }
    __builtin_amdgcn_sched_barrier(0);

    // ---- outputs (off the critical chain) ----
    int bglob = grp * GB + eb;
    int hglob = n0 + ej;
    *(float2*)(out + ((size_t)bglob * SS + t) * HH + hglob) =
        make_float2(hv[0], hv[1]);
    if (t == SS - 1) {
      size_t base = (size_t)BB * SS * HH;
      *(float2*)(out + base + (size_t)bglob * HH + hglob) =
          make_float2(hv[0], hv[1]);                        // h_f
      *(float2*)(out + base + (size_t)BB * HH + (size_t)bglob * HH + hglob) =
          make_float2(cs0, cs1);                            // c_f
    }
  }
}

extern "C" void kernel_launch(void* const* d_in, const int* in_sizes, int n_in,
                              void* d_out, int out_size, void* d_ws, size_t ws_size,
                              hipStream_t stream) {
  const float* x = (const float*)d_in[0];     // [64,512,256]
  const float* W = (const float*)d_in[1];     // [256,2048]
  const float* U = (const float*)d_in[2];     // [512,2048]
  const float* bias = (const float*)d_in[3];  // [2048]
  float* out = (float*)d_out;

  // ws layout byte-identical to R6 (no growth):
  char* ws = (char*)d_ws;
  u64t* hpub = (u64t*)ws;                                   // 256 KB
  __hip_bfloat16* Wt = (__hip_bfloat16*)(ws + 256 * 1024);  // 1 MB
  __hip_bfloat16* xb =
      (__hip_bfloat16*)(ws + 256 * 1024 + (size_t)G4 * II * 2);  // 16 MB

  // claim counters: last 64B of out (c_f tail). Claims all complete before
  // any WG steps (arrival barrier); the region is legitimately rewritten
  // with real c_f values at t=SS-1.
  unsigned* cnt = (unsigned*)((char*)d_out + out_size - 64);

  // zero hpub (tag 0 == epoch of h(-1), payload 0 == h(-1)=0) + counters
  hipMemsetAsync(d_ws, 0, 256 * 1024, stream);
  hipMemsetAsync(cnt, 0, 64, stream);
  convert_x_kernel<<<BB * SS, II, 0, stream>>>(x, xb);
  transpose_w_kernel<<<128, 256, 0, stream>>>(W, Wt);
  // 256 WGs: LDS forces 1 WG/CU -> full chip; 64 claim work, rest exit.
  lstm_step<<<256, 256, 0, stream>>>(U, bias, xb, Wt, hpub, cnt, out);
}